// Round 3
// baseline (6029.952 us; speedup 1.0000x reference)
//
#include <hip/hip_runtime.h>
#include <math.h>

#define N_NODES 10000
#define N_EDGES 320000

// ---------------- edge_index dtype detection ----------------
// Reference builds edge_index as int64. If the harness hands us raw int64,
// every odd 32-bit word is 0 (values in [0,10000)). With int32, odd words are
// random node ids — P(256 consecutive zeros) ~ 0.
__global__ void k_detect(const int* __restrict__ ei, int* __restrict__ flag) {
  __shared__ int any_nz;
  if (threadIdx.x == 0) any_nz = 0;
  __syncthreads();
  if (ei[2 * threadIdx.x + 1] != 0) atomicOr(&any_nz, 1);
  __syncthreads();
  if (threadIdx.x == 0) *flag = (any_nz == 0) ? 1 : 0;  // 1 => int64 layout
}

__device__ __forceinline__ int2 load_edge(const int* __restrict__ ei, int e, int is64) {
  if (is64) return make_int2(ei[2 * e], ei[2 * N_EDGES + 2 * e]);
  return make_int2(ei[e], ei[N_EDGES + e]);
}

// ---------------- preprocessing ----------------

__global__ void k_init(float* __restrict__ deg, int* __restrict__ cnt) {
  int i = blockIdx.x * blockDim.x + threadIdx.x;
  if (i < N_NODES) { deg[i] = 0.f; cnt[i] = 0; }
}

__global__ void k_deg(const int* __restrict__ ei, const float* __restrict__ w,
                      const int* __restrict__ flag,
                      float* __restrict__ deg, int* __restrict__ cnt) {
  const int is64 = *flag;
  int e = blockIdx.x * blockDim.x + threadIdx.x;
  if (e < N_EDGES) {
    int2 sd = load_edge(ei, e, is64);
    atomicAdd(&deg[sd.x], w[e]);   // deg = segment_sum(edge_weight, src)
    atomicAdd(&cnt[sd.y], 1);      // CSR row sizes (by dst)
  }
}

// single-block: dis = deg>0 ? rsqrt(deg) : 0 ; exclusive-scan cnt -> row_ptr ; zero cursors
__global__ __launch_bounds__(1024) void k_scan(const float* __restrict__ deg,
                                               float* __restrict__ dis,
                                               const int* __restrict__ cnt,
                                               int* __restrict__ row_ptr,
                                               int* __restrict__ cur) {
  __shared__ int sbuf[1024];
  const int tid = threadIdx.x;
  for (int i = tid; i < N_NODES; i += 1024) {
    float d = deg[i];
    dis[i] = d > 0.f ? 1.f / sqrtf(d) : 0.f;
    cur[i] = 0;
  }
  __syncthreads();
  int run = 0;
  for (int base = 0; base < N_NODES; base += 1024) {
    int v = (base + tid < N_NODES) ? cnt[base + tid] : 0;
    sbuf[tid] = v;
    __syncthreads();
    for (int o = 1; o < 1024; o <<= 1) {            // Hillis-Steele inclusive scan
      int t = (tid >= o) ? sbuf[tid - o] : 0;
      __syncthreads();
      sbuf[tid] += t;
      __syncthreads();
    }
    if (base + tid < N_NODES) row_ptr[base + tid + 1] = run + sbuf[tid];
    int tot = sbuf[1023];
    __syncthreads();
    run += tot;
  }
  if (tid == 0) row_ptr[0] = 0;
}

// fill packed edge array: edat[p] = {src, bitcast(wn)}
__global__ void k_fill(const int* __restrict__ ei, const float* __restrict__ w,
                       const int* __restrict__ flag, const float* __restrict__ dis,
                       const int* __restrict__ row_ptr, int* __restrict__ cur,
                       int2* __restrict__ edat) {
  const int is64 = *flag;
  int e = blockIdx.x * blockDim.x + threadIdx.x;
  if (e < N_EDGES) {
    int2 sd = load_edge(ei, e, is64);
    int p = row_ptr[sd.y] + atomicAdd(&cur[sd.y], 1);
    float v = -dis[sd.x] * w[e] * dis[sd.y];   // wn for L_hat = -D^-1/2 A D^-1/2
    edat[p] = make_int2(sd.x, __float_as_int(v));
  }
}

// transpose W (K,CI,CO) -> Wt (K,CO,CI)  [coalesced read, strided write; one-time]
__global__ void k_tr(const float* __restrict__ W, float* __restrict__ Wt,
                     int K, int CI, int CO) {
  int i = blockIdx.x * blockDim.x + threadIdx.x;
  int tot = K * CI * CO;
  if (i < tot) {
    int k = i / (CI * CO), r = i % (CI * CO);
    int ci = r / CO, co = r % CO;
    Wt[k * CI * CO + co * CI + ci] = W[i];
  }
}

// ---------------- fused Chebyshev step ----------------
// One wave per node. t buffers padded to stride 64 (aligned 4-line gathers).
// Edge data packed int2; gather loop loads 2 edges per int4. GEMM uses transposed
// W (float4 per lane) and ds_read_b128 broadcasts of the per-wave t row.
// No __syncthreads: all LDS is wave-private.

template <int CIN, int COUT, int SIN, bool FIRST, bool LAST>
__global__ __launch_bounds__(256) void k_cheb(
    const int* __restrict__ row_ptr, const int2* __restrict__ edat,
    const float* __restrict__ t_cur,   // layer input when FIRST (stride SIN), else stride ST
    const float* __restrict__ t_prev,  // unused when FIRST
    int sprev,                          // runtime stride of t_prev
    float* __restrict__ t_next,        // stride ST
    const float* __restrict__ Wkt,     // transposed W[k] slice [COUT][CIN]
    const float* __restrict__ W0t,     // FIRST only, transposed W[0]
    const float* __restrict__ bias,    // FIRST only
    float* __restrict__ acc,
    float* __restrict__ h_out)         // LAST only (stride 64)
{
  constexpr int ST = (CIN == 2) ? 2 : 64;           // t buffer stride
  constexpr int SCUR = FIRST ? SIN : ST;            // stride of t_cur
  __shared__ __align__(16) float ts[4][(CIN > 4) ? 64 : 1];
  __shared__ __align__(16) float xs[4][(FIRST && CIN > 4) ? 64 : 1];
  const int wid = threadIdx.x >> 6, lane = threadIdx.x & 63;
  const int node = blockIdx.x * 4 + wid;   // 10000 % 4 == 0
  const int start = row_ptr[node], end = row_ptr[node + 1];

  float tn0 = 0.f, tn1 = 0.f;  // CIN==2 results (all lanes)

  if constexpr (CIN == 2) {
    float s0 = 0.f, s1 = 0.f;
    for (int e = start + lane; e < end; e += 64) {
      int2 ed = edat[e];
      float wv = __int_as_float(ed.y);
      float2 v = *reinterpret_cast<const float2*>(t_cur + ed.x * SCUR);
      s0 += wv * v.x; s1 += wv * v.y;
    }
#pragma unroll
    for (int o = 32; o; o >>= 1) { s0 += __shfl_xor(s0, o); s1 += __shfl_xor(s1, o); }
    if constexpr (FIRST) { tn0 = s0; tn1 = s1; }
    else {
      tn0 = 2.f * s0 - t_prev[node * sprev];
      tn1 = 2.f * s1 - t_prev[node * sprev + 1];
    }
    if (lane == 0) *reinterpret_cast<float2*>(t_next + node * ST) = make_float2(tn0, tn1);
  } else {
    const int cl = (lane < CIN) ? lane : 0;
    float a0 = 0.f, a1 = 0.f, a2 = 0.f, a3 = 0.f;
    int e = start;
    if (e < end && (e & 1)) {                       // peel to 16B-align int4 loads
      int2 ed = edat[e];
      a0 += __int_as_float(ed.y) * t_cur[ed.x * SCUR + cl];
      e++;
    }
    for (; e + 3 < end; e += 4) {                   // 2 x int4 = 4 edges, 4 gathers in flight
      int4 p0 = *reinterpret_cast<const int4*>(edat + e);
      int4 p1 = *reinterpret_cast<const int4*>(edat + e + 2);
      a0 += __int_as_float(p0.y) * t_cur[p0.x * SCUR + cl];
      a1 += __int_as_float(p0.w) * t_cur[p0.z * SCUR + cl];
      a2 += __int_as_float(p1.y) * t_cur[p1.x * SCUR + cl];
      a3 += __int_as_float(p1.w) * t_cur[p1.z * SCUR + cl];
    }
    for (; e < end; e++) {
      int2 ed = edat[e];
      a0 += __int_as_float(ed.y) * t_cur[ed.x * SCUR + cl];
    }
    float p = (a0 + a1) + (a2 + a3);
    float tn;
    if constexpr (FIRST) tn = p;
    else tn = 2.f * p - t_prev[node * sprev + cl];
    if (lane < CIN) {
      t_next[node * ST + lane] = tn;
      ts[wid][lane] = tn;
      if constexpr (FIRST) xs[wid][lane] = t_cur[node * SIN + lane];
    }
    __builtin_amdgcn_wave_barrier();  // order LDS write -> read within the wave
  }

  if (lane < COUT) {
    float sum;
    if constexpr (FIRST) sum = bias[lane];
    else sum = acc[node * COUT + lane];
    if constexpr (CIN == 2) {
      const float2 wk = *reinterpret_cast<const float2*>(Wkt + lane * 2);
      sum += tn0 * wk.x + tn1 * wk.y;
      if constexpr (FIRST) {
        const float2 w0 = *reinterpret_cast<const float2*>(W0t + lane * 2);
        float x0 = t_cur[node * SIN], x1 = t_cur[node * SIN + 1];
        sum += x0 * w0.x + x1 * w0.y;
      }
    } else {
      const float4* wrow = reinterpret_cast<const float4*>(Wkt + lane * CIN);
#pragma unroll
      for (int c4 = 0; c4 < CIN / 4; c4++) {
        float4 w = wrow[c4];
        float4 t = *reinterpret_cast<const float4*>(&ts[wid][c4 * 4]);  // b128 broadcast
        sum += w.x * t.x + w.y * t.y + w.z * t.z + w.w * t.w;
      }
      if constexpr (FIRST) {
        const float4* w0row = reinterpret_cast<const float4*>(W0t + lane * CIN);
#pragma unroll
        for (int c4 = 0; c4 < CIN / 4; c4++) {
          float4 w = w0row[c4];
          float4 t = *reinterpret_cast<const float4*>(&xs[wid][c4 * 4]);
          sum += w.x * t.x + w.y * t.y + w.z * t.z + w.w * t.w;
        }
      }
    }
    if constexpr (LAST) {
      h_out[node * 64 + lane] = sum / (1.f + expf(-sum));  // silu
    } else {
      acc[node * COUT + lane] = sum;
    }
  }
}

// final layer: out = sigmoid(h3 @ W4), W4 is (30,); h3 stride 64
__global__ __launch_bounds__(256) void k_out(const float* __restrict__ h3,
                                             const float* __restrict__ W4,
                                             float* __restrict__ out) {
  const int wid = threadIdx.x >> 6, lane = threadIdx.x & 63;
  const int node = blockIdx.x * 4 + wid;
  float v = (lane < 30) ? h3[node * 64 + lane] * W4[lane] : 0.f;
#pragma unroll
  for (int o = 32; o; o >>= 1) v += __shfl_xor(v, o);
  if (lane == 0) out[node] = 1.f / (1.f + expf(-v));
}

// ---------------- host-side layer driver ----------------

template <int CI, int CO, int SIN>
static void run_layer(const float* h_in, float* h_out, const float* Wt, const float* b, int K,
                      const int* rowp, const int2* edat,
                      float* tA, float* tB, float* tC, float* accb, hipStream_t stream) {
  const int GB = N_NODES / 4;
  constexpr int ST = (CI == 2) ? 2 : 64;
  (void)ST;
  k_cheb<CI, CO, SIN, true, false><<<GB, 256, 0, stream>>>(
      rowp, edat, h_in, nullptr, 0, tA, Wt + CI * CO, Wt, b, accb, nullptr);
  float* ptrs[3] = {tA, tB, tC};
  for (int k = 2; k < K; k++) {
    const float* prev = (k == 2) ? h_in : ptrs[(k - 3) % 3];
    int sprev = (k == 2) ? SIN : ST;
    const float* cur  = ptrs[(k - 2) % 3];
    float* next       = ptrs[(k - 1) % 3];
    if (k < K - 1)
      k_cheb<CI, CO, SIN, false, false><<<GB, 256, 0, stream>>>(
          rowp, edat, cur, prev, sprev, next, Wt + (size_t)k * CI * CO, nullptr, nullptr,
          accb, nullptr);
    else
      k_cheb<CI, CO, SIN, false, true><<<GB, 256, 0, stream>>>(
          rowp, edat, cur, prev, sprev, next, Wt + (size_t)k * CI * CO, nullptr, nullptr,
          accb, h_out);
  }
}

extern "C" void kernel_launch(void* const* d_in, const int* in_sizes, int n_in,
                              void* d_out, int out_size, void* d_ws, size_t ws_size,
                              hipStream_t stream) {
  const float* x  = (const float*)d_in[0];
  const int*   ei = (const int*)d_in[1];   // (2, E), int32 or raw int64 (detected)
  const float* ew = (const float*)d_in[2];
  const float* W1 = (const float*)d_in[3];
  const float* b1 = (const float*)d_in[4];
  const float* W2 = (const float*)d_in[5];
  const float* b2 = (const float*)d_in[6];
  const float* W3 = (const float*)d_in[7];
  const float* b3 = (const float*)d_in[8];
  const float* W4 = (const float*)d_in[9];
  float* out = (float*)d_out;

  // workspace carve-out (~22 MB total)
  char* ws = (char*)d_ws;
  size_t off = 0;
  auto alloc = [&](size_t bytes) {
    void* p = ws + off;
    off += (bytes + 255) & ~size_t(255);
    return p;
  };
  float* deg  = (float*)alloc(N_NODES * 4);
  float* dis  = (float*)alloc(N_NODES * 4);
  int*   cnt  = (int*)alloc(N_NODES * 4);
  int*   cur  = (int*)alloc(N_NODES * 4);
  int*   rowp = (int*)alloc((N_NODES + 1) * 4);
  int2*  edat = (int2*)alloc(N_EDGES * 8);
  int*   flag = (int*)alloc(256);
  float* Wt1  = (float*)alloc(200 * 2 * 60 * 4);
  float* Wt2  = (float*)alloc(200 * 60 * 60 * 4);
  float* Wt3  = (float*)alloc(20 * 60 * 30 * 4);
  float* tA   = (float*)alloc(N_NODES * 64 * 4);   // padded stride 64
  float* tB   = (float*)alloc(N_NODES * 64 * 4);
  float* tC   = (float*)alloc(N_NODES * 64 * 4);
  float* accb = (float*)alloc(N_NODES * 60 * 4);
  float* h1   = (float*)alloc(N_NODES * 64 * 4);
  float* h2   = (float*)alloc(N_NODES * 64 * 4);
  float* h3   = (float*)alloc(N_NODES * 64 * 4);

  // build normalized-Laplacian CSR (by dst) each call (ws is re-poisoned)
  k_detect<<<1, 256, 0, stream>>>(ei, flag);
  k_init<<<(N_NODES + 255) / 256, 256, 0, stream>>>(deg, cnt);
  k_deg<<<(N_EDGES + 255) / 256, 256, 0, stream>>>(ei, ew, flag, deg, cnt);
  k_scan<<<1, 1024, 0, stream>>>(deg, dis, cnt, rowp, cur);
  k_fill<<<(N_EDGES + 255) / 256, 256, 0, stream>>>(ei, ew, flag, dis, rowp, cur, edat);

  // transpose weights (one-time per call)
  k_tr<<<(200 * 2 * 60 + 255) / 256, 256, 0, stream>>>(W1, Wt1, 200, 2, 60);
  k_tr<<<(200 * 60 * 60 + 255) / 256, 256, 0, stream>>>(W2, Wt2, 200, 60, 60);
  k_tr<<<(20 * 60 * 30 + 255) / 256, 256, 0, stream>>>(W3, Wt3, 20, 60, 30);

  run_layer<2, 60, 2>(x, h1, Wt1, b1, 200, rowp, edat, tA, tB, tC, accb, stream);
  run_layer<60, 60, 64>(h1, h2, Wt2, b2, 200, rowp, edat, tA, tB, tC, accb, stream);
  run_layer<60, 30, 64>(h2, h3, Wt3, b3, 20, rowp, edat, tA, tB, tC, accb, stream);
  k_out<<<N_NODES / 4, 256, 0, stream>>>(h3, W4, out);
}